// Round 3
// baseline (10452.055 us; speedup 1.0000x reference)
//
#include <hip/hip_runtime.h>

#define T_STEPS 12
#define NN      50000
#define EE      800000
#define IN_F    12
#define HID     128
#define G3      384
#define BB      4096
#define AF_     10
#define BN_EPS  1e-5f

#define ALIGN_UP(x) (((x) + 255) & ~(size_t)255)

// total scratch need (bytes), carved identically from d_ws or static pool
#define SZ_DEG    ALIGN_UP((size_t)NN * 4)
#define SZ_RP     ALIGN_UP((size_t)(NN + 1) * 4)
#define SZ_CUR    ALIGN_UP((size_t)NN * 4)
#define SZ_COL    ALIGN_UP((size_t)EE * 4)
#define SZ_XIN12  ALIGN_UP((size_t)NN * IN_F * 4)
#define SZ_NH     ALIGN_UP((size_t)NN * HID * 4)
#define SZ_NG3    ALIGN_UP((size_t)NN * G3 * 4)
#define WS_NEED   (SZ_DEG + SZ_RP + SZ_CUR + SZ_COL + SZ_XIN12 + 5 * SZ_NH + 2 * SZ_NG3)

__device__ __align__(256) char g_static_pool[WS_NEED];

// ---------------- bail path ----------------
__global__ void zero_out_kernel(float* out, int n) {
    int i = blockIdx.x * blockDim.x + threadIdx.x;
    if (i < n) out[i] = 0.f;
}

// ---------------- init: zero deg, h1, h2 ----------------
__global__ void init_kernel(int* deg, float* h1, float* h2) {
    int i = blockIdx.x * blockDim.x + threadIdx.x;
    if (i < NN) deg[i] = 0;
    if (i < NN * HID) { h1[i] = 0.f; h2[i] = 0.f; }
}

// ---------------- CSR build ----------------
__global__ void hist_kernel(const int* __restrict__ dst, int* __restrict__ deg, int E) {
    int e = blockIdx.x * blockDim.x + threadIdx.x;
    if (e < E) {
        unsigned d = (unsigned)dst[e];
        if (d < NN) atomicAdd(&deg[d], 1);
    }
}

__global__ __launch_bounds__(1024) void scan_kernel(const int* __restrict__ deg,
                                                    int* __restrict__ row_ptr,
                                                    int* __restrict__ cursor, int n) {
    __shared__ int sd[1024];
    __shared__ int carry_s;
    int tid = threadIdx.x;
    if (tid == 0) { carry_s = 0; row_ptr[0] = 0; }
    __syncthreads();
    for (int base = 0; base < n; base += 1024) {
        int i = base + tid;
        int v = (i < n) ? deg[i] : 0;
        sd[tid] = v;
        __syncthreads();
        for (int off = 1; off < 1024; off <<= 1) {
            int val = (tid >= off) ? sd[tid - off] : 0;
            __syncthreads();
            sd[tid] += val;
            __syncthreads();
        }
        int carry = carry_s;
        if (i < n) {
            int incl = carry + sd[tid];
            row_ptr[i + 1] = incl;
            cursor[i] = incl - v;  // exclusive prefix
        }
        __syncthreads();
        if (tid == 0) carry_s = carry + sd[1023];
        __syncthreads();
    }
}

__global__ void scatter_kernel(const int* __restrict__ src, const int* __restrict__ dst,
                               int* __restrict__ cursor, int* __restrict__ col, int E) {
    int e = blockIdx.x * blockDim.x + threadIdx.x;
    if (e < E) {
        unsigned d = (unsigned)dst[e];
        if (d < NN) {
            int pos = atomicAdd(&cursor[d], 1);
            if ((unsigned)pos < (unsigned)EE) col[pos] = src[e];
        }
    }
}

// ---------------- conv1 aggregation (12 features) ----------------
__global__ void agg12_kernel(const float* __restrict__ x, const int* __restrict__ rp,
                             const int* __restrict__ col, float* __restrict__ out, int E) {
    int g = blockIdx.x * blockDim.x + threadIdx.x;
    if (g >= NN * IN_F) return;
    int i = g / IN_F;
    int f = g - i * IN_F;
    float s = x[g];
    int e0 = rp[i], e1 = rp[i + 1];
    if (e1 > E) e1 = E;
    for (int e = e0; e < e1; ++e) {
        unsigned c = (unsigned)col[e];
        if (c < NN) s += x[c * IN_F + f];
    }
    out[g] = s;
}

// ---------------- MLP1 layer1 (K=12) + ReLU + BN ----------------
__global__ __launch_bounds__(256) void mlp1a_kernel(const float* __restrict__ xin,
                                                    const float* __restrict__ W1, const float* __restrict__ b1,
                                                    const float* __restrict__ gg, const float* __restrict__ be,
                                                    const float* __restrict__ rm, const float* __restrict__ rv,
                                                    float* __restrict__ out) {
    __shared__ float xr[2][IN_F];
    int i0 = blockIdx.x * 2;
    int tid = threadIdx.x;
    if (tid < 2 * IN_F) {
        int r = tid / IN_F, f = tid - r * IN_F;
        xr[r][f] = (i0 + r < NN) ? xin[(size_t)(i0 + r) * IN_F + f] : 0.f;
    }
    __syncthreads();
    int r = tid >> 7, j = tid & 127;
    int i = i0 + r;
    if (i >= NN) return;
    float s = b1[j];
#pragma unroll
    for (int k = 0; k < IN_F; ++k) s += xr[r][k] * W1[j * IN_F + k];
    s = fmaxf(s, 0.f);
    float sc = gg[j] * rsqrtf(rv[j] + BN_EPS);
    out[(size_t)i * HID + j] = (s - rm[j]) * sc + be[j];
}

// ---------------- generic GEMM: C[n x mcols] = act(A[n x 128] @ W[mcols x 128]^T + b) ----------------
// act: 0 = none, 1 = relu, 2 = relu then BN affine
#define SWZC(r, k) ((k) ^ (((r) & 7) << 2))
__global__ __launch_bounds__(256) void gemm128_kernel(const float* __restrict__ A, const float* __restrict__ W,
                                                      const float* __restrict__ bias,
                                                      const float* __restrict__ bn_g, const float* __restrict__ bn_be,
                                                      const float* __restrict__ bn_rm, const float* __restrict__ bn_rv,
                                                      float* __restrict__ C, int n, int mcols, int act) {
    __shared__ float As[64][128];
    __shared__ float Ws[64][128];
    int row0 = blockIdx.x * 64, col0 = blockIdx.y * 64;
    int tid = threadIdx.x;
    for (int idx = tid; idx < 64 * 32; idx += 256) {
        int r = idx >> 5;
        int c4 = (idx & 31) * 4;
        int cs = SWZC(r, c4);  // xor bits 2..4; float4 groups stay contiguous & aligned
        int gr = row0 + r;
        float4 va = (gr < n) ? *(const float4*)(A + (size_t)gr * HID + c4) : make_float4(0, 0, 0, 0);
        *(float4*)&As[r][cs] = va;
        float4 vw = *(const float4*)(W + (size_t)(col0 + r) * HID + c4);
        *(float4*)&Ws[r][cs] = vw;
    }
    __syncthreads();
    int tx = tid & 15, ty = tid >> 4;
    float acc[4][4] = {};
    int vy = (ty & 7) << 2;
    int vx = (tx & 7) << 2;
#pragma unroll 4
    for (int k = 0; k < 128; ++k) {
        int ka = k ^ vy;
        int kw = k ^ vx;
        float a0 = As[ty][ka], a1 = As[ty + 16][ka], a2 = As[ty + 32][ka], a3 = As[ty + 48][ka];
        float w0 = Ws[tx][kw], w1 = Ws[tx + 16][kw], w2 = Ws[tx + 32][kw], w3 = Ws[tx + 48][kw];
        acc[0][0] += a0 * w0; acc[0][1] += a0 * w1; acc[0][2] += a0 * w2; acc[0][3] += a0 * w3;
        acc[1][0] += a1 * w0; acc[1][1] += a1 * w1; acc[1][2] += a1 * w2; acc[1][3] += a1 * w3;
        acc[2][0] += a2 * w0; acc[2][1] += a2 * w1; acc[2][2] += a2 * w2; acc[2][3] += a2 * w3;
        acc[3][0] += a3 * w0; acc[3][1] += a3 * w1; acc[3][2] += a3 * w2; acc[3][3] += a3 * w3;
    }
#pragma unroll
    for (int m = 0; m < 4; ++m) {
        int r = row0 + ty + 16 * m;
        if (r >= n) continue;
#pragma unroll
        for (int q = 0; q < 4; ++q) {
            int c = col0 + tx + 16 * q;
            float v = acc[m][q] + bias[c];
            if (act == 1) {
                v = fmaxf(v, 0.f);
            } else if (act == 2) {
                v = fmaxf(v, 0.f);
                float sc = bn_g[c] * rsqrtf(bn_rv[c] + BN_EPS);
                v = (v - bn_rm[c]) * sc + bn_be[c];
            }
            C[(size_t)r * mcols + c] = v;
        }
    }
}

// ---------------- GRU gate fusion ----------------
__global__ void gru_gate_kernel(const float* __restrict__ gi, const float* __restrict__ gh,
                                float* __restrict__ h) {
    int idx = blockIdx.x * blockDim.x + threadIdx.x;
    if (idx >= NN * HID) return;
    int i = idx >> 7, j = idx & 127;
    const float* pi = gi + (size_t)i * G3;
    const float* ph = gh + (size_t)i * G3;
    float r = 1.f / (1.f + expf(-(pi[j] + ph[j])));
    float z = 1.f / (1.f + expf(-(pi[HID + j] + ph[HID + j])));
    float nn = tanhf(pi[2 * HID + j] + r * ph[2 * HID + j]);
    h[idx] = (1.f - z) * nn + z * h[idx];
}

// ---------------- conv2 aggregation (128 features) ----------------
__global__ __launch_bounds__(128) void agg128_kernel(const float* __restrict__ x, const int* __restrict__ rp,
                                                     const int* __restrict__ col, float* __restrict__ out, int E) {
    int i = blockIdx.x;
    int j = threadIdx.x;
    float s = x[(size_t)i * HID + j];
    int e0 = rp[i], e1 = rp[i + 1];
    if (e1 > E) e1 = E;
    for (int e = e0; e < e1; ++e) {
        unsigned c = (unsigned)col[e];
        if (c < NN) s += x[(size_t)c * HID + j];
    }
    out[(size_t)i * HID + j] = s;
}

// ---------------- head: gather + fc1(leaky .1) + fc2(leaky .05) + fc3 ----------------
__global__ __launch_bounds__(64) void head_kernel(const float* __restrict__ h2, const int* __restrict__ tidx,
                                                  const float* __restrict__ apart,
                                                  const float* __restrict__ w1, const float* __restrict__ b1,
                                                  const float* __restrict__ w2, const float* __restrict__ b2,
                                                  const float* __restrict__ w3, const float* __restrict__ b3,
                                                  float* __restrict__ out) {
    __shared__ float feat[HID + AF_];
    __shared__ float o1[64];
    __shared__ float o2[32];
    int b = blockIdx.x;
    int t = threadIdx.x;
    unsigned node = (unsigned)tidx[b];
    if (node >= NN) node = 0;
    for (int k = t; k < HID; k += 64) feat[k] = h2[(size_t)node * HID + k];
    if (t < AF_) feat[HID + t] = apart[(size_t)b * AF_ + t];
    __syncthreads();
    {
        float s = b1[t];
        for (int k = 0; k < HID + AF_; ++k) s += feat[k] * w1[t * (HID + AF_) + k];
        o1[t] = (s > 0.f) ? s : 0.1f * s;
    }
    __syncthreads();
    if (t < 32) {
        float s = b2[t];
        for (int k = 0; k < 64; ++k) s += o1[k] * w2[t * 64 + k];
        o2[t] = (s > 0.f) ? s : 0.05f * s;
    }
    __syncthreads();
    if (t == 0) {
        float s = b3[0];
        for (int k = 0; k < 32; ++k) s += o2[k] * w3[k];
        out[b] = s;
    }
}

extern "C" void kernel_launch(void* const* d_in, const int* in_sizes, int n_in,
                              void* d_out, int out_size, void* d_ws, size_t ws_size,
                              hipStream_t stream) {
    // ---- strict input-mapping validation (prevents OOB weight reads = HSA abort) ----
    // dict order: x_seq, apart, edge_src, edge_dst, target_idx, weights...
    // sig  order: x_seq, apart, weights..., edge_src, edge_dst, target_idx
    int ie_src = -1, ie_dst = -1, ie_tidx = -1, iw0 = -1;
    bool ok = false;
    if (n_in >= 31 && in_sizes[0] == T_STEPS * NN * IN_F && in_sizes[1] == BB * AF_) {
        if (in_sizes[2] > 100000 && in_sizes[3] == in_sizes[2] && in_sizes[4] == BB &&
            in_sizes[5] == HID * IN_F && in_sizes[11] == HID * HID &&
            in_sizes[21] == G3 * HID && in_sizes[22] == G3 * HID &&
            in_sizes[25] == 64 * (HID + AF_)) {
            ie_src = 2; ie_dst = 3; ie_tidx = 4; iw0 = 5; ok = true;
        } else if (in_sizes[2] == HID * IN_F && in_sizes[8] == HID * HID &&
                   in_sizes[18] == G3 * HID && in_sizes[19] == G3 * HID &&
                   in_sizes[22] == 64 * (HID + AF_) &&
                   in_sizes[28] > 100000 && in_sizes[29] == in_sizes[28] && in_sizes[30] == BB) {
            iw0 = 2; ie_src = 28; ie_dst = 29; ie_tidx = 30; ok = true;
        }
    }
    if (!ok) {  // clean diagnosable bail: zero output, no crash
        zero_out_kernel<<<(out_size + 255) / 256, 256, 0, stream>>>((float*)d_out, out_size);
        return;
    }

    const float* x_seq  = (const float*)d_in[0];
    const float* apart  = (const float*)d_in[1];
    const int*   e_src  = (const int*)d_in[ie_src];
    const int*   e_dst  = (const int*)d_in[ie_dst];
    const int*   t_idx  = (const int*)d_in[ie_tidx];
    const float* c1_w1 = (const float*)d_in[iw0 + 0];
    const float* c1_b1 = (const float*)d_in[iw0 + 1];
    const float* c1_g  = (const float*)d_in[iw0 + 2];
    const float* c1_be = (const float*)d_in[iw0 + 3];
    const float* c1_rm = (const float*)d_in[iw0 + 4];
    const float* c1_rv = (const float*)d_in[iw0 + 5];
    const float* c1_w2 = (const float*)d_in[iw0 + 6];
    const float* c1_b2 = (const float*)d_in[iw0 + 7];
    const float* c2_w1 = (const float*)d_in[iw0 + 8];
    const float* c2_b1 = (const float*)d_in[iw0 + 9];
    const float* c2_g  = (const float*)d_in[iw0 + 10];
    const float* c2_be = (const float*)d_in[iw0 + 11];
    const float* c2_rm = (const float*)d_in[iw0 + 12];
    const float* c2_rv = (const float*)d_in[iw0 + 13];
    const float* c2_w2 = (const float*)d_in[iw0 + 14];
    const float* c2_b2 = (const float*)d_in[iw0 + 15];
    const float* g_wih = (const float*)d_in[iw0 + 16];
    const float* g_whh = (const float*)d_in[iw0 + 17];
    const float* g_bih = (const float*)d_in[iw0 + 18];
    const float* g_bhh = (const float*)d_in[iw0 + 19];
    const float* f1_w  = (const float*)d_in[iw0 + 20];
    const float* f1_b  = (const float*)d_in[iw0 + 21];
    const float* f2_w  = (const float*)d_in[iw0 + 22];
    const float* f2_b  = (const float*)d_in[iw0 + 23];
    const float* f3_w  = (const float*)d_in[iw0 + 24];
    const float* f3_b  = (const float*)d_in[iw0 + 25];

    int E = in_sizes[ie_src];
    if (E > EE) E = EE;

    // ---- scratch: prefer d_ws if large enough, else static pool ----
    char* base;
    if (ws_size >= WS_NEED) {
        base = (char*)d_ws;
    } else {
        void* sp = nullptr;
        hipGetSymbolAddress(&sp, HIP_SYMBOL(g_static_pool));
        if (sp == nullptr) {  // cannot proceed safely
            zero_out_kernel<<<(out_size + 255) / 256, 256, 0, stream>>>((float*)d_out, out_size);
            return;
        }
        base = (char*)sp;
    }
    size_t off = 0;
    auto nxt = [&](size_t bytes) { char* p = base + off; off += bytes; return p; };
    int*   deg     = (int*)nxt(SZ_DEG);
    int*   row_ptr = (int*)nxt(SZ_RP);
    int*   cursor  = (int*)nxt(SZ_CUR);
    int*   col     = (int*)nxt(SZ_COL);
    float* xin12   = (float*)nxt(SZ_XIN12);
    float* t1      = (float*)nxt(SZ_NH);
    float* t2      = (float*)nxt(SZ_NH);
    float* xin2    = (float*)nxt(SZ_NH);
    float* h1      = (float*)nxt(SZ_NH);
    float* h2      = (float*)nxt(SZ_NH);
    float* gi      = (float*)nxt(SZ_NG3);
    float* gh      = (float*)nxt(SZ_NG3);

    init_kernel<<<(NN * HID + 255) / 256, 256, 0, stream>>>(deg, h1, h2);

    // CSR build (by dst; col holds src)
    hist_kernel<<<(E + 255) / 256, 256, 0, stream>>>(e_dst, deg, E);
    scan_kernel<<<1, 1024, 0, stream>>>(deg, row_ptr, cursor, NN);
    scatter_kernel<<<(E + 255) / 256, 256, 0, stream>>>(e_src, e_dst, cursor, col, E);

    dim3 gemm_grid128((NN + 63) / 64, 2);
    dim3 gemm_grid384((NN + 63) / 64, 6);
    int elem_grid = (NN * HID + 255) / 256;

    for (int t = 0; t < T_STEPS; ++t) {
        const float* xt = x_seq + (size_t)t * NN * IN_F;
        // conv1: agg + MLP(12->128 relu BN, 128->128 relu)
        agg12_kernel<<<(NN * IN_F + 255) / 256, 256, 0, stream>>>(xt, row_ptr, col, xin12, E);
        mlp1a_kernel<<<NN / 2, 256, 0, stream>>>(xin12, c1_w1, c1_b1, c1_g, c1_be, c1_rm, c1_rv, t1);
        gemm128_kernel<<<gemm_grid128, 256, 0, stream>>>(t1, c1_w2, c1_b2, nullptr, nullptr, nullptr, nullptr,
                                                         t2, NN, HID, 1);
        // GRU1 step: h1 <- GRU(t2, h1)
        gemm128_kernel<<<gemm_grid384, 256, 0, stream>>>(t2, g_wih, g_bih, nullptr, nullptr, nullptr, nullptr,
                                                         gi, NN, G3, 0);
        gemm128_kernel<<<gemm_grid384, 256, 0, stream>>>(h1, g_whh, g_bhh, nullptr, nullptr, nullptr, nullptr,
                                                         gh, NN, G3, 0);
        gru_gate_kernel<<<elem_grid, 256, 0, stream>>>(gi, gh, h1);
        // conv2 on seq_t = h1
        agg128_kernel<<<NN, 128, 0, stream>>>(h1, row_ptr, col, xin2, E);
        gemm128_kernel<<<gemm_grid128, 256, 0, stream>>>(xin2, c2_w1, c2_b1, c2_g, c2_be, c2_rm, c2_rv,
                                                         t1, NN, HID, 2);
        gemm128_kernel<<<gemm_grid128, 256, 0, stream>>>(t1, c2_w2, c2_b2, nullptr, nullptr, nullptr, nullptr,
                                                         t2, NN, HID, 1);
        // GRU2 step: h2 <- GRU(t2, h2)  (same weights)
        gemm128_kernel<<<gemm_grid384, 256, 0, stream>>>(t2, g_wih, g_bih, nullptr, nullptr, nullptr, nullptr,
                                                         gi, NN, G3, 0);
        gemm128_kernel<<<gemm_grid384, 256, 0, stream>>>(h2, g_whh, g_bhh, nullptr, nullptr, nullptr, nullptr,
                                                         gh, NN, G3, 0);
        gru_gate_kernel<<<elem_grid, 256, 0, stream>>>(gi, gh, h2);
    }

    head_kernel<<<BB, 64, 0, stream>>>(h2, t_idx, apart, f1_w, f1_b, f2_w, f2_b, f3_w, f3_b, (float*)d_out);
}

// Round 4
// 4180.169 us; speedup vs baseline: 2.5004x; 2.5004x over previous
//
#include <hip/hip_runtime.h>

#define T_STEPS 12
#define NN      50000
#define EE      800000
#define IN_F    12
#define HID     128
#define G3      384
#define BB      4096
#define AF_     10
#define BN_EPS  1e-5f

typedef unsigned short ushort_t;
typedef __attribute__((ext_vector_type(8))) short bf16x8;
typedef __attribute__((ext_vector_type(4))) float f32x4;

__device__ inline float b2f(ushort_t u) { return __uint_as_float(((unsigned)u) << 16); }
__device__ inline ushort_t f2b(float f) {
    unsigned u = __float_as_uint(f);
    return (ushort_t)((u + 0x7fffu + ((u >> 16) & 1u)) >> 16);
}
__device__ inline float sigm(float x) { return 1.f / (1.f + expf(-x)); }

#define ALIGN_UP(x) (((x) + 255) & ~(size_t)255)
#define SZ_DEG    ALIGN_UP((size_t)NN * 4)
#define SZ_RP     ALIGN_UP((size_t)(NN + 1) * 4)
#define SZ_CUR    ALIGN_UP((size_t)NN * 4)
#define SZ_COL    ALIGN_UP((size_t)EE * 4)
#define SZ_XIN12  ALIGN_UP((size_t)NN * IN_F * 4)
#define SZ_NHB    ALIGN_UP((size_t)NN * HID * 2)          // bf16 N x 128
#define SZ_W128   ALIGN_UP((size_t)HID * HID * 2)         // bf16 128 x 128
#define SZ_WGRU   ALIGN_UP((size_t)G3 * HID * 2)          // bf16 384 x 128
#define WS_NEED   (SZ_DEG + SZ_RP + SZ_CUR + SZ_COL + SZ_XIN12 + 5 * SZ_NHB + 3 * SZ_W128 + 2 * SZ_WGRU)

__device__ __align__(256) char g_static_pool[WS_NEED];

// ---------------- bail path ----------------
__global__ void zero_out_kernel(float* out, int n) {
    int i = blockIdx.x * blockDim.x + threadIdx.x;
    if (i < n) out[i] = 0.f;
}

// ---------------- weight fp32 -> bf16 ----------------
__global__ void cvt_kernel(const float* __restrict__ in, ushort_t* __restrict__ out, int n) {
    int i = blockIdx.x * blockDim.x + threadIdx.x;
    if (i < n) out[i] = f2b(in[i]);
}

// ---------------- init: zero deg, h1, h2 ----------------
__global__ void init_kernel(int* deg, ushort_t* h1, ushort_t* h2) {
    int i = blockIdx.x * blockDim.x + threadIdx.x;
    if (i < NN) deg[i] = 0;
    if (i < NN * HID) { h1[i] = 0; h2[i] = 0; }
}

// ---------------- CSR build ----------------
__global__ void hist_kernel(const int* __restrict__ dst, int* __restrict__ deg, int E) {
    int e = blockIdx.x * blockDim.x + threadIdx.x;
    if (e < E) {
        unsigned d = (unsigned)dst[e];
        if (d < NN) atomicAdd(&deg[d], 1);
    }
}

__global__ __launch_bounds__(1024) void scan_kernel(const int* __restrict__ deg,
                                                    int* __restrict__ row_ptr,
                                                    int* __restrict__ cursor, int n) {
    __shared__ int sd[1024];
    __shared__ int carry_s;
    int tid = threadIdx.x;
    if (tid == 0) { carry_s = 0; row_ptr[0] = 0; }
    __syncthreads();
    for (int base = 0; base < n; base += 1024) {
        int i = base + tid;
        int v = (i < n) ? deg[i] : 0;
        sd[tid] = v;
        __syncthreads();
        for (int off = 1; off < 1024; off <<= 1) {
            int val = (tid >= off) ? sd[tid - off] : 0;
            __syncthreads();
            sd[tid] += val;
            __syncthreads();
        }
        int carry = carry_s;
        if (i < n) {
            int incl = carry + sd[tid];
            row_ptr[i + 1] = incl;
            cursor[i] = incl - v;
        }
        __syncthreads();
        if (tid == 0) carry_s = carry + sd[1023];
        __syncthreads();
    }
}

__global__ void scatter_kernel(const int* __restrict__ src, const int* __restrict__ dst,
                               int* __restrict__ cursor, int* __restrict__ col, int E) {
    int e = blockIdx.x * blockDim.x + threadIdx.x;
    if (e < E) {
        unsigned d = (unsigned)dst[e];
        if (d < NN) {
            int pos = atomicAdd(&cursor[d], 1);
            if ((unsigned)pos < (unsigned)EE) col[pos] = src[e];
        }
    }
}

// ---------------- conv1 aggregation (12 features, fp32) ----------------
__global__ void agg12_kernel(const float* __restrict__ x, const int* __restrict__ rp,
                             const int* __restrict__ col, float* __restrict__ out, int E) {
    int g = blockIdx.x * blockDim.x + threadIdx.x;
    if (g >= NN * IN_F) return;
    int i = g / IN_F;
    int f = g - i * IN_F;
    float s = x[g];
    int e0 = rp[i], e1 = rp[i + 1];
    if (e1 > E) e1 = E;
    for (int e = e0; e < e1; ++e) {
        unsigned c = (unsigned)col[e];
        if (c < NN) s += x[c * IN_F + f];
    }
    out[g] = s;
}

// ---------------- MLP1 layer1 (K=12, fp32 math) + ReLU + BN -> bf16 ----------------
__global__ __launch_bounds__(256) void mlp1a_kernel(const float* __restrict__ xin,
                                                    const float* __restrict__ W1, const float* __restrict__ b1,
                                                    const float* __restrict__ gg, const float* __restrict__ be,
                                                    const float* __restrict__ rm, const float* __restrict__ rv,
                                                    ushort_t* __restrict__ out) {
    __shared__ float xr[2][IN_F];
    int i0 = blockIdx.x * 2;
    int tid = threadIdx.x;
    if (tid < 2 * IN_F) {
        int r = tid / IN_F, f = tid - r * IN_F;
        xr[r][f] = (i0 + r < NN) ? xin[(size_t)(i0 + r) * IN_F + f] : 0.f;
    }
    __syncthreads();
    int r = tid >> 7, j = tid & 127;
    int i = i0 + r;
    if (i >= NN) return;
    float s = b1[j];
#pragma unroll
    for (int k = 0; k < IN_F; ++k) s += xr[r][k] * W1[j * IN_F + k];
    s = fmaxf(s, 0.f);
    float sc = gg[j] * rsqrtf(rv[j] + BN_EPS);
    out[(size_t)i * HID + j] = f2b((s - rm[j]) * sc + be[j]);
}

// ---------------- MFMA conv GEMM: C[N x 128] = act(A @ W^T + b), bf16 in/out ----------------
// block 512 = 8 waves; wave w -> cols [w*16, w*16+16); 32 rows/block (2 row-tiles/wave).
// act: 1 = relu, 2 = relu then BN affine
__global__ __launch_bounds__(512) void gemm_conv_kernel(const ushort_t* __restrict__ A,
                                                        const ushort_t* __restrict__ W,
                                                        const float* __restrict__ bias,
                                                        const float* __restrict__ bn_g, const float* __restrict__ bn_be,
                                                        const float* __restrict__ bn_rm, const float* __restrict__ bn_rv,
                                                        ushort_t* __restrict__ C, int act) {
    int tid = threadIdx.x;
    int wave = tid >> 6, lane = tid & 63;
    int li = lane & 15, ks = lane >> 4;
    int r0 = blockIdx.x * 32;
    int j0 = wave * 16;
    int ra0 = min(r0 + li, NN - 1);
    int ra1 = min(r0 + 16 + li, NN - 1);
    const ushort_t* pa0 = A + (size_t)ra0 * HID + ks * 8;
    const ushort_t* pa1 = A + (size_t)ra1 * HID + ks * 8;
    const ushort_t* pw  = W + (size_t)(j0 + li) * HID + ks * 8;
    f32x4 acc0 = {0.f, 0.f, 0.f, 0.f}, acc1 = {0.f, 0.f, 0.f, 0.f};
#pragma unroll
    for (int k0 = 0; k0 < HID; k0 += 32) {
        bf16x8 b = *(const bf16x8*)(pw + k0);
        bf16x8 a0 = *(const bf16x8*)(pa0 + k0);
        bf16x8 a1 = *(const bf16x8*)(pa1 + k0);
        acc0 = __builtin_amdgcn_mfma_f32_16x16x32_bf16(a0, b, acc0, 0, 0, 0);
        acc1 = __builtin_amdgcn_mfma_f32_16x16x32_bf16(a1, b, acc1, 0, 0, 0);
    }
    int jc = j0 + li;
    float bsum = bias[jc];
    float sc = 1.f, sh = 0.f;
    if (act == 2) {
        sc = bn_g[jc] * rsqrtf(bn_rv[jc] + BN_EPS);
        sh = bn_be[jc] - bn_rm[jc] * sc;
    }
#pragma unroll
    for (int q = 0; q < 4; ++q) {
        int rowA = r0 + ks * 4 + q;
        int rowB = rowA + 16;
        float v0 = fmaxf(acc0[q] + bsum, 0.f);
        float v1 = fmaxf(acc1[q] + bsum, 0.f);
        if (act == 2) { v0 = v0 * sc + sh; v1 = v1 * sc + sh; }
        if (rowA < NN) C[(size_t)rowA * HID + jc] = f2b(v0);
        if (rowB < NN) C[(size_t)rowB * HID + jc] = f2b(v1);
    }
}

// ---------------- fused GRU step: h <- GRU(x, h), bf16 in/out, all gates in-register ----------------
// block 512 = 8 waves; wave w -> gate cols [w*16, w*16+16); 32 rows/block.
__global__ __launch_bounds__(512) void fused_gru_kernel(const ushort_t* __restrict__ x,
                                                        ushort_t* __restrict__ h,
                                                        const ushort_t* __restrict__ wih,
                                                        const ushort_t* __restrict__ whh,
                                                        const float* __restrict__ bih,
                                                        const float* __restrict__ bhh) {
    int tid = threadIdx.x;
    int wave = tid >> 6, lane = tid & 63;
    int li = lane & 15, ks = lane >> 4;
    int r0 = blockIdx.x * 32;
    int j0 = wave * 16;
    int ra0 = min(r0 + li, NN - 1);
    int ra1 = min(r0 + 16 + li, NN - 1);
    const ushort_t* px0 = x + (size_t)ra0 * HID + ks * 8;
    const ushort_t* px1 = x + (size_t)ra1 * HID + ks * 8;
    const ushort_t* ph0 = h + (size_t)ra0 * HID + ks * 8;
    const ushort_t* ph1 = h + (size_t)ra1 * HID + ks * 8;
    const ushort_t* pwr = wih + (size_t)(j0 + li) * HID + ks * 8;
    const ushort_t* pwz = wih + (size_t)(HID + j0 + li) * HID + ks * 8;
    const ushort_t* pwn = wih + (size_t)(2 * HID + j0 + li) * HID + ks * 8;
    const ushort_t* pvr = whh + (size_t)(j0 + li) * HID + ks * 8;
    const ushort_t* pvz = whh + (size_t)(HID + j0 + li) * HID + ks * 8;
    const ushort_t* pvn = whh + (size_t)(2 * HID + j0 + li) * HID + ks * 8;
    f32x4 ir0 = {0,0,0,0}, iz0 = {0,0,0,0}, in0 = {0,0,0,0};
    f32x4 hr0 = {0,0,0,0}, hz0 = {0,0,0,0}, hn0 = {0,0,0,0};
    f32x4 ir1 = {0,0,0,0}, iz1 = {0,0,0,0}, in1 = {0,0,0,0};
    f32x4 hr1 = {0,0,0,0}, hz1 = {0,0,0,0}, hn1 = {0,0,0,0};
#pragma unroll
    for (int k0 = 0; k0 < HID; k0 += 32) {
        bf16x8 ax0 = *(const bf16x8*)(px0 + k0);
        bf16x8 ax1 = *(const bf16x8*)(px1 + k0);
        bf16x8 ah0 = *(const bf16x8*)(ph0 + k0);
        bf16x8 ah1 = *(const bf16x8*)(ph1 + k0);
        bf16x8 br = *(const bf16x8*)(pwr + k0);
        bf16x8 bz = *(const bf16x8*)(pwz + k0);
        bf16x8 bn = *(const bf16x8*)(pwn + k0);
        bf16x8 cr = *(const bf16x8*)(pvr + k0);
        bf16x8 cz = *(const bf16x8*)(pvz + k0);
        bf16x8 cn = *(const bf16x8*)(pvn + k0);
        ir0 = __builtin_amdgcn_mfma_f32_16x16x32_bf16(ax0, br, ir0, 0, 0, 0);
        ir1 = __builtin_amdgcn_mfma_f32_16x16x32_bf16(ax1, br, ir1, 0, 0, 0);
        iz0 = __builtin_amdgcn_mfma_f32_16x16x32_bf16(ax0, bz, iz0, 0, 0, 0);
        iz1 = __builtin_amdgcn_mfma_f32_16x16x32_bf16(ax1, bz, iz1, 0, 0, 0);
        in0 = __builtin_amdgcn_mfma_f32_16x16x32_bf16(ax0, bn, in0, 0, 0, 0);
        in1 = __builtin_amdgcn_mfma_f32_16x16x32_bf16(ax1, bn, in1, 0, 0, 0);
        hr0 = __builtin_amdgcn_mfma_f32_16x16x32_bf16(ah0, cr, hr0, 0, 0, 0);
        hr1 = __builtin_amdgcn_mfma_f32_16x16x32_bf16(ah1, cr, hr1, 0, 0, 0);
        hz0 = __builtin_amdgcn_mfma_f32_16x16x32_bf16(ah0, cz, hz0, 0, 0, 0);
        hz1 = __builtin_amdgcn_mfma_f32_16x16x32_bf16(ah1, cz, hz1, 0, 0, 0);
        hn0 = __builtin_amdgcn_mfma_f32_16x16x32_bf16(ah0, cn, hn0, 0, 0, 0);
        hn1 = __builtin_amdgcn_mfma_f32_16x16x32_bf16(ah1, cn, hn1, 0, 0, 0);
    }
    int jc = j0 + li;
    float bi_r = bih[jc], bi_z = bih[HID + jc], bi_n = bih[2 * HID + jc];
    float bh_r = bhh[jc], bh_z = bhh[HID + jc], bh_n = bhh[2 * HID + jc];
    // prefetch old h for this lane's 8 output cells (reads must precede any write)
    float holdA[4], holdB[4];
#pragma unroll
    for (int q = 0; q < 4; ++q) {
        int rowA = min(r0 + ks * 4 + q, NN - 1);
        int rowB = min(r0 + 16 + ks * 4 + q, NN - 1);
        holdA[q] = b2f(h[(size_t)rowA * HID + jc]);
        holdB[q] = b2f(h[(size_t)rowB * HID + jc]);
    }
    __syncthreads();  // all reads of h (frags + hold) block-wide complete before in-place writes
#pragma unroll
    for (int q = 0; q < 4; ++q) {
        int rowA = r0 + ks * 4 + q;
        int rowB = rowA + 16;
        {
            float rg = sigm(ir0[q] + bi_r + hr0[q] + bh_r);
            float zg = sigm(iz0[q] + bi_z + hz0[q] + bh_z);
            float ng = tanhf(in0[q] + bi_n + rg * (hn0[q] + bh_n));
            float hv = (1.f - zg) * ng + zg * holdA[q];
            if (rowA < NN) h[(size_t)rowA * HID + jc] = f2b(hv);
        }
        {
            float rg = sigm(ir1[q] + bi_r + hr1[q] + bh_r);
            float zg = sigm(iz1[q] + bi_z + hz1[q] + bh_z);
            float ng = tanhf(in1[q] + bi_n + rg * (hn1[q] + bh_n));
            float hv = (1.f - zg) * ng + zg * holdB[q];
            if (rowB < NN) h[(size_t)rowB * HID + jc] = f2b(hv);
        }
    }
}

// ---------------- conv2 aggregation (128 bf16 features), one wave per node ----------------
__global__ __launch_bounds__(256) void agg128b_kernel(const ushort_t* __restrict__ x,
                                                      const int* __restrict__ rp,
                                                      const int* __restrict__ col,
                                                      ushort_t* __restrict__ out, int E) {
    int node = (blockIdx.x * 256 + threadIdx.x) >> 6;
    int lane = threadIdx.x & 63;
    if (node >= NN) return;
    unsigned v = *(const unsigned*)(x + (size_t)node * HID + lane * 2);
    float s0 = b2f((ushort_t)(v & 0xffff));
    float s1 = b2f((ushort_t)(v >> 16));
    int e0 = rp[node], e1 = rp[node + 1];
    if (e1 > E) e1 = E;
    for (int e = e0; e < e1; ++e) {
        unsigned c = (unsigned)col[e];
        if (c < NN) {
            unsigned u = *(const unsigned*)(x + (size_t)c * HID + lane * 2);
            s0 += b2f((ushort_t)(u & 0xffff));
            s1 += b2f((ushort_t)(u >> 16));
        }
    }
    unsigned o = (unsigned)f2b(s0) | ((unsigned)f2b(s1) << 16);
    *(unsigned*)(out + (size_t)node * HID + lane * 2) = o;
}

// ---------------- head: gather + fc1(leaky .1) + fc2(leaky .05) + fc3 ----------------
__global__ __launch_bounds__(64) void head_kernel(const ushort_t* __restrict__ h2, const int* __restrict__ tidx,
                                                  const float* __restrict__ apart,
                                                  const float* __restrict__ w1, const float* __restrict__ b1,
                                                  const float* __restrict__ w2, const float* __restrict__ b2,
                                                  const float* __restrict__ w3, const float* __restrict__ b3,
                                                  float* __restrict__ out) {
    __shared__ float feat[HID + AF_];
    __shared__ float o1[64];
    __shared__ float o2[32];
    int b = blockIdx.x;
    int t = threadIdx.x;
    unsigned node = (unsigned)tidx[b];
    if (node >= NN) node = 0;
    for (int k = t; k < HID; k += 64) feat[k] = b2f(h2[(size_t)node * HID + k]);
    if (t < AF_) feat[HID + t] = apart[(size_t)b * AF_ + t];
    __syncthreads();
    {
        float s = b1[t];
        for (int k = 0; k < HID + AF_; ++k) s += feat[k] * w1[t * (HID + AF_) + k];
        o1[t] = (s > 0.f) ? s : 0.1f * s;
    }
    __syncthreads();
    if (t < 32) {
        float s = b2[t];
        for (int k = 0; k < 64; ++k) s += o1[k] * w2[t * 64 + k];
        o2[t] = (s > 0.f) ? s : 0.05f * s;
    }
    __syncthreads();
    if (t == 0) {
        float s = b3[0];
        for (int k = 0; k < 32; ++k) s += o2[k] * w3[k];
        out[b] = s;
    }
}

extern "C" void kernel_launch(void* const* d_in, const int* in_sizes, int n_in,
                              void* d_out, int out_size, void* d_ws, size_t ws_size,
                              hipStream_t stream) {
    // ---- strict input-mapping validation ----
    int ie_src = -1, ie_dst = -1, ie_tidx = -1, iw0 = -1;
    bool ok = false;
    if (n_in >= 31 && in_sizes[0] == T_STEPS * NN * IN_F && in_sizes[1] == BB * AF_) {
        if (in_sizes[2] > 100000 && in_sizes[3] == in_sizes[2] && in_sizes[4] == BB &&
            in_sizes[5] == HID * IN_F && in_sizes[11] == HID * HID &&
            in_sizes[21] == G3 * HID && in_sizes[22] == G3 * HID &&
            in_sizes[25] == 64 * (HID + AF_)) {
            ie_src = 2; ie_dst = 3; ie_tidx = 4; iw0 = 5; ok = true;
        } else if (in_sizes[2] == HID * IN_F && in_sizes[8] == HID * HID &&
                   in_sizes[18] == G3 * HID && in_sizes[19] == G3 * HID &&
                   in_sizes[22] == 64 * (HID + AF_) &&
                   in_sizes[28] > 100000 && in_sizes[29] == in_sizes[28] && in_sizes[30] == BB) {
            iw0 = 2; ie_src = 28; ie_dst = 29; ie_tidx = 30; ok = true;
        }
    }
    if (!ok) {
        zero_out_kernel<<<(out_size + 255) / 256, 256, 0, stream>>>((float*)d_out, out_size);
        return;
    }

    const float* x_seq  = (const float*)d_in[0];
    const float* apart  = (const float*)d_in[1];
    const int*   e_src  = (const int*)d_in[ie_src];
    const int*   e_dst  = (const int*)d_in[ie_dst];
    const int*   t_idx  = (const int*)d_in[ie_tidx];
    const float* c1_w1 = (const float*)d_in[iw0 + 0];
    const float* c1_b1 = (const float*)d_in[iw0 + 1];
    const float* c1_g  = (const float*)d_in[iw0 + 2];
    const float* c1_be = (const float*)d_in[iw0 + 3];
    const float* c1_rm = (const float*)d_in[iw0 + 4];
    const float* c1_rv = (const float*)d_in[iw0 + 5];
    const float* c1_w2 = (const float*)d_in[iw0 + 6];
    const float* c1_b2 = (const float*)d_in[iw0 + 7];
    const float* c2_w1 = (const float*)d_in[iw0 + 8];
    const float* c2_b1 = (const float*)d_in[iw0 + 9];
    const float* c2_g  = (const float*)d_in[iw0 + 10];
    const float* c2_be = (const float*)d_in[iw0 + 11];
    const float* c2_rm = (const float*)d_in[iw0 + 12];
    const float* c2_rv = (const float*)d_in[iw0 + 13];
    const float* c2_w2 = (const float*)d_in[iw0 + 14];
    const float* c2_b2 = (const float*)d_in[iw0 + 15];
    const float* g_wih = (const float*)d_in[iw0 + 16];
    const float* g_whh = (const float*)d_in[iw0 + 17];
    const float* g_bih = (const float*)d_in[iw0 + 18];
    const float* g_bhh = (const float*)d_in[iw0 + 19];
    const float* f1_w  = (const float*)d_in[iw0 + 20];
    const float* f1_b  = (const float*)d_in[iw0 + 21];
    const float* f2_w  = (const float*)d_in[iw0 + 22];
    const float* f2_b  = (const float*)d_in[iw0 + 23];
    const float* f3_w  = (const float*)d_in[iw0 + 24];
    const float* f3_b  = (const float*)d_in[iw0 + 25];

    int E = in_sizes[ie_src];
    if (E > EE) E = EE;

    // ---- scratch ----
    char* base;
    if (ws_size >= WS_NEED) {
        base = (char*)d_ws;
    } else {
        void* sp = nullptr;
        hipGetSymbolAddress(&sp, HIP_SYMBOL(g_static_pool));
        if (sp == nullptr) {
            zero_out_kernel<<<(out_size + 255) / 256, 256, 0, stream>>>((float*)d_out, out_size);
            return;
        }
        base = (char*)sp;
    }
    size_t off = 0;
    auto nxt = [&](size_t bytes) { char* p = base + off; off += bytes; return p; };
    int*      deg     = (int*)nxt(SZ_DEG);
    int*      row_ptr = (int*)nxt(SZ_RP);
    int*      cursor  = (int*)nxt(SZ_CUR);
    int*      col     = (int*)nxt(SZ_COL);
    float*    xin12   = (float*)nxt(SZ_XIN12);
    ushort_t* t1      = (ushort_t*)nxt(SZ_NHB);
    ushort_t* t2      = (ushort_t*)nxt(SZ_NHB);
    ushort_t* xin2    = (ushort_t*)nxt(SZ_NHB);
    ushort_t* h1      = (ushort_t*)nxt(SZ_NHB);
    ushort_t* h2      = (ushort_t*)nxt(SZ_NHB);
    ushort_t* wb_c1w2 = (ushort_t*)nxt(SZ_W128);
    ushort_t* wb_c2w1 = (ushort_t*)nxt(SZ_W128);
    ushort_t* wb_c2w2 = (ushort_t*)nxt(SZ_W128);
    ushort_t* wb_wih  = (ushort_t*)nxt(SZ_WGRU);
    ushort_t* wb_whh  = (ushort_t*)nxt(SZ_WGRU);

    // weight conversion (tiny)
    cvt_kernel<<<(HID * HID + 255) / 256, 256, 0, stream>>>(c1_w2, wb_c1w2, HID * HID);
    cvt_kernel<<<(HID * HID + 255) / 256, 256, 0, stream>>>(c2_w1, wb_c2w1, HID * HID);
    cvt_kernel<<<(HID * HID + 255) / 256, 256, 0, stream>>>(c2_w2, wb_c2w2, HID * HID);
    cvt_kernel<<<(G3 * HID + 255) / 256, 256, 0, stream>>>(g_wih, wb_wih, G3 * HID);
    cvt_kernel<<<(G3 * HID + 255) / 256, 256, 0, stream>>>(g_whh, wb_whh, G3 * HID);

    init_kernel<<<(NN * HID + 255) / 256, 256, 0, stream>>>(deg, h1, h2);

    // CSR build (by dst; col holds src)
    hist_kernel<<<(E + 255) / 256, 256, 0, stream>>>(e_dst, deg, E);
    scan_kernel<<<1, 1024, 0, stream>>>(deg, row_ptr, cursor, NN);
    scatter_kernel<<<(E + 255) / 256, 256, 0, stream>>>(e_src, e_dst, cursor, col, E);

    const int gemm_grid = (NN + 31) / 32;  // 32 rows/block

    for (int t = 0; t < T_STEPS; ++t) {
        const float* xt = x_seq + (size_t)t * NN * IN_F;
        // conv1
        agg12_kernel<<<(NN * IN_F + 255) / 256, 256, 0, stream>>>(xt, row_ptr, col, xin12, E);
        mlp1a_kernel<<<NN / 2, 256, 0, stream>>>(xin12, c1_w1, c1_b1, c1_g, c1_be, c1_rm, c1_rv, t1);
        gemm_conv_kernel<<<gemm_grid, 512, 0, stream>>>(t1, wb_c1w2, c1_b2, nullptr, nullptr, nullptr, nullptr, t2, 1);
        // GRU1
        fused_gru_kernel<<<gemm_grid, 512, 0, stream>>>(t2, h1, wb_wih, wb_whh, g_bih, g_bhh);
        // conv2
        agg128b_kernel<<<(NN * 64 + 255) / 256, 256, 0, stream>>>(h1, row_ptr, col, xin2, E);
        gemm_conv_kernel<<<gemm_grid, 512, 0, stream>>>(xin2, wb_c2w1, c2_b1, c2_g, c2_be, c2_rm, c2_rv, t1, 2);
        gemm_conv_kernel<<<gemm_grid, 512, 0, stream>>>(t1, wb_c2w2, c2_b2, nullptr, nullptr, nullptr, nullptr, t2, 1);
        // GRU2 (same weights)
        fused_gru_kernel<<<gemm_grid, 512, 0, stream>>>(t2, h2, wb_wih, wb_whh, g_bih, g_bhh);
    }

    head_kernel<<<BB, 64, 0, stream>>>(h2, t_idx, apart, f1_w, f1_b, f2_w, f2_b, f3_w, f3_b, (float*)d_out);
}

// Round 5
// 2696.433 us; speedup vs baseline: 3.8763x; 1.5503x over previous
//
#include <hip/hip_runtime.h>

#define T_STEPS 12
#define NN      50000
#define EE      800000
#define IN_F    12
#define HID     128
#define G3      384
#define BB      4096
#define AF_     10
#define BN_EPS  1e-5f
#define LPAD    136   // LDS row stride (bf16): 272B -> 2-way-free bank pattern

typedef unsigned short ushort_t;
typedef __attribute__((ext_vector_type(8))) short bf16x8;
typedef __attribute__((ext_vector_type(4))) float f32x4;

#define MFMA(a, b, c) __builtin_amdgcn_mfma_f32_16x16x32_bf16((a), (b), (c), 0, 0, 0)

__device__ inline float b2f(ushort_t u) { return __uint_as_float(((unsigned)u) << 16); }
__device__ inline ushort_t f2b(float f) {
    unsigned u = __float_as_uint(f);
    return (ushort_t)((u + 0x7fffu + ((u >> 16) & 1u)) >> 16);
}
__device__ inline float sigm(float x) { return 1.f / (1.f + expf(-x)); }

#define ALIGN_UP(x) (((x) + 255) & ~(size_t)255)
#define SZ_DEG    ALIGN_UP((size_t)NN * 4)
#define SZ_RP     ALIGN_UP((size_t)(NN + 1) * 4)
#define SZ_CUR    ALIGN_UP((size_t)NN * 4)
#define SZ_COL    ALIGN_UP((size_t)EE * 4)
#define SZ_XIN12  ALIGN_UP((size_t)NN * IN_F * 4)
#define SZ_NHB    ALIGN_UP((size_t)NN * HID * 2)
#define SZ_W128   ALIGN_UP((size_t)HID * HID * 2)
#define SZ_WGRU   ALIGN_UP((size_t)G3 * HID * 2)
#define WS_NEED   (SZ_DEG + SZ_RP + SZ_CUR + SZ_COL + SZ_XIN12 + 3 * SZ_NHB + 3 * SZ_W128 + 2 * SZ_WGRU)

__device__ __align__(256) char g_static_pool[WS_NEED];

// ---------------- bail path ----------------
__global__ void zero_out_kernel(float* out, int n) {
    int i = blockIdx.x * blockDim.x + threadIdx.x;
    if (i < n) out[i] = 0.f;
}

// ---------------- weights fp32 -> bf16 (all five in one launch) ----------------
__global__ void cvt5_kernel(const float* s0, ushort_t* d0, int n0,
                            const float* s1, ushort_t* d1, int n1,
                            const float* s2, ushort_t* d2, int n2,
                            const float* s3, ushort_t* d3, int n3,
                            const float* s4, ushort_t* d4, int n4) {
    int i = blockIdx.x * blockDim.x + threadIdx.x;
    if (i < n0) d0[i] = f2b(s0[i]);
    i -= n0;
    if (i >= 0 && i < n1) d1[i] = f2b(s1[i]);
    i -= n1;
    if (i >= 0 && i < n2) d2[i] = f2b(s2[i]);
    i -= n2;
    if (i >= 0 && i < n3) d3[i] = f2b(s3[i]);
    i -= n3;
    if (i >= 0 && i < n4) d4[i] = f2b(s4[i]);
}

// ---------------- init: zero deg, h1, h2 ----------------
__global__ void init_kernel(int* deg, ushort_t* h1, ushort_t* h2) {
    int i = blockIdx.x * blockDim.x + threadIdx.x;
    if (i < NN) deg[i] = 0;
    if (i < NN * HID) { h1[i] = 0; h2[i] = 0; }
}

// ---------------- CSR build ----------------
__global__ void hist_kernel(const int* __restrict__ dst, int* __restrict__ deg, int E) {
    int e = blockIdx.x * blockDim.x + threadIdx.x;
    if (e < E) {
        unsigned d = (unsigned)dst[e];
        if (d < NN) atomicAdd(&deg[d], 1);
    }
}

// shuffle-based single-block scan: ~3 barriers/chunk (vs ~20 Hillis-Steele)
__global__ __launch_bounds__(1024) void scan_kernel(const int* __restrict__ deg,
                                                    int* __restrict__ row_ptr,
                                                    int* __restrict__ cursor, int n) {
    __shared__ int wsum[16];
    __shared__ int carry_s;
    int tid = threadIdx.x;
    int wid = tid >> 6, lane = tid & 63;
    if (tid == 0) { carry_s = 0; row_ptr[0] = 0; }
    __syncthreads();
    for (int base = 0; base < n; base += 1024) {
        int i = base + tid;
        int v = (i < n) ? deg[i] : 0;
        int x = v;
#pragma unroll
        for (int off = 1; off < 64; off <<= 1) {
            int t = __shfl_up(x, (unsigned)off);
            if (lane >= off) x += t;
        }
        if (lane == 63) wsum[wid] = x;
        __syncthreads();
        if (tid == 0) {
            int a = 0;
#pragma unroll
            for (int w = 0; w < 16; ++w) { int t = wsum[w]; wsum[w] = a; a += t; }
        }
        __syncthreads();
        int incl = carry_s + wsum[wid] + x;
        if (i < n) {
            row_ptr[i + 1] = incl;
            cursor[i] = incl - v;
        }
        __syncthreads();
        if (tid == 1023) carry_s = incl;
        __syncthreads();
    }
}

__global__ void scatter_kernel(const int* __restrict__ src, const int* __restrict__ dst,
                               int* __restrict__ cursor, int* __restrict__ col, int E) {
    int e = blockIdx.x * blockDim.x + threadIdx.x;
    if (e < E) {
        unsigned d = (unsigned)dst[e];
        if (d < NN) {
            int pos = atomicAdd(&cursor[d], 1);
            if ((unsigned)pos < (unsigned)EE) col[pos] = src[e];
        }
    }
}

// ---------------- conv1 aggregation (12 features, fp32) ----------------
__global__ void agg12_kernel(const float* __restrict__ x, const int* __restrict__ rp,
                             const int* __restrict__ col, float* __restrict__ out, int E) {
    int g = blockIdx.x * blockDim.x + threadIdx.x;
    if (g >= NN * IN_F) return;
    int i = g / IN_F;
    int f = g - i * IN_F;
    float s = x[g];
    int e0 = rp[i], e1 = rp[i + 1];
    if (e1 > E) e1 = E;
    for (int e = e0; e < e1; ++e) {
        unsigned c = (unsigned)col[e];
        if (c < NN) s += x[c * IN_F + f];
    }
    out[g] = s;
}

// ---------------- shared GRU phase: h(rows r0..r0+31) <- GRU(x from LDS, h), in place ----------------
__device__ __forceinline__ void gru_phase(const ushort_t (*xl)[LPAD], ushort_t* __restrict__ h,
                                          const ushort_t* __restrict__ wih, const ushort_t* __restrict__ whh,
                                          const float* __restrict__ bih, const float* __restrict__ bhh,
                                          int r0, int li, int ks, int wave) {
    int j0 = wave * 16;
    int ra0 = min(r0 + li, NN - 1);
    int ra1 = min(r0 + 16 + li, NN - 1);
    const ushort_t* ph0 = h + (size_t)ra0 * HID + ks * 8;
    const ushort_t* ph1 = h + (size_t)ra1 * HID + ks * 8;
    const ushort_t* pwr = wih + (size_t)(j0 + li) * HID + ks * 8;
    const ushort_t* pwz = wih + (size_t)(HID + j0 + li) * HID + ks * 8;
    const ushort_t* pwn = wih + (size_t)(2 * HID + j0 + li) * HID + ks * 8;
    const ushort_t* pvr = whh + (size_t)(j0 + li) * HID + ks * 8;
    const ushort_t* pvz = whh + (size_t)(HID + j0 + li) * HID + ks * 8;
    const ushort_t* pvn = whh + (size_t)(2 * HID + j0 + li) * HID + ks * 8;
    f32x4 ir0 = {0,0,0,0}, iz0 = {0,0,0,0}, in0 = {0,0,0,0};
    f32x4 hr0 = {0,0,0,0}, hz0 = {0,0,0,0}, hn0 = {0,0,0,0};
    f32x4 ir1 = {0,0,0,0}, iz1 = {0,0,0,0}, in1 = {0,0,0,0};
    f32x4 hr1 = {0,0,0,0}, hz1 = {0,0,0,0}, hn1 = {0,0,0,0};
#pragma unroll
    for (int k0 = 0; k0 < HID; k0 += 32) {
        bf16x8 ax0 = *(const bf16x8*)&xl[li][ks * 8 + k0];
        bf16x8 ax1 = *(const bf16x8*)&xl[li + 16][ks * 8 + k0];
        bf16x8 ah0 = *(const bf16x8*)(ph0 + k0);
        bf16x8 ah1 = *(const bf16x8*)(ph1 + k0);
        bf16x8 br = *(const bf16x8*)(pwr + k0);
        bf16x8 bz = *(const bf16x8*)(pwz + k0);
        bf16x8 bn = *(const bf16x8*)(pwn + k0);
        bf16x8 cr = *(const bf16x8*)(pvr + k0);
        bf16x8 cz = *(const bf16x8*)(pvz + k0);
        bf16x8 cn = *(const bf16x8*)(pvn + k0);
        ir0 = MFMA(ax0, br, ir0); ir1 = MFMA(ax1, br, ir1);
        iz0 = MFMA(ax0, bz, iz0); iz1 = MFMA(ax1, bz, iz1);
        in0 = MFMA(ax0, bn, in0); in1 = MFMA(ax1, bn, in1);
        hr0 = MFMA(ah0, cr, hr0); hr1 = MFMA(ah1, cr, hr1);
        hz0 = MFMA(ah0, cz, hz0); hz1 = MFMA(ah1, cz, hz1);
        hn0 = MFMA(ah0, cn, hn0); hn1 = MFMA(ah1, cn, hn1);
    }
    int jc = j0 + li;
    float bi_r = bih[jc], bi_z = bih[HID + jc], bi_n = bih[2 * HID + jc];
    float bh_r = bhh[jc], bh_z = bhh[HID + jc], bh_n = bhh[2 * HID + jc];
    float holdA[4], holdB[4];
#pragma unroll
    for (int q = 0; q < 4; ++q) {
        int rowA = min(r0 + ks * 4 + q, NN - 1);
        int rowB = min(r0 + 16 + ks * 4 + q, NN - 1);
        holdA[q] = b2f(h[(size_t)rowA * HID + jc]);
        holdB[q] = b2f(h[(size_t)rowB * HID + jc]);
    }
    __syncthreads();  // all reads of h block-wide complete before in-place writes
#pragma unroll
    for (int q = 0; q < 4; ++q) {
        int rowA = r0 + ks * 4 + q;
        int rowB = rowA + 16;
        {
            float rg = sigm(ir0[q] + bi_r + hr0[q] + bh_r);
            float zg = sigm(iz0[q] + bi_z + hz0[q] + bh_z);
            float ng = tanhf(in0[q] + bi_n + rg * (hn0[q] + bh_n));
            float hv = (1.f - zg) * ng + zg * holdA[q];
            if (rowA < NN) h[(size_t)rowA * HID + jc] = f2b(hv);
        }
        {
            float rg = sigm(ir1[q] + bi_r + hr1[q] + bh_r);
            float zg = sigm(iz1[q] + bi_z + hz1[q] + bh_z);
            float ng = tanhf(in1[q] + bi_n + rg * (hn1[q] + bh_n));
            float hv = (1.f - zg) * ng + zg * holdB[q];
            if (rowB < NN) h[(size_t)rowB * HID + jc] = f2b(hv);
        }
    }
}

// ---------------- mega1: mlp1-layer1(VALU,K=12)+BN -> LDS -> layer2 MFMA -> LDS -> GRU1 ----------------
__global__ __launch_bounds__(512) void mega1_kernel(const float* __restrict__ xin12,
                                                    ushort_t* __restrict__ h,
                                                    const float* __restrict__ W1, const float* __restrict__ b1,
                                                    const float* __restrict__ gg, const float* __restrict__ be,
                                                    const float* __restrict__ rm, const float* __restrict__ rv,
                                                    const ushort_t* __restrict__ w2b, const float* __restrict__ b2,
                                                    const ushort_t* __restrict__ wih, const ushort_t* __restrict__ whh,
                                                    const float* __restrict__ bih, const float* __restrict__ bhh) {
    __shared__ float xs[32][IN_F];
    __shared__ ushort_t l1[32][LPAD];
    __shared__ ushort_t l2[32][LPAD];
    int tid = threadIdx.x;
    int wave = tid >> 6, lane = tid & 63;
    int li = lane & 15, ks = lane >> 4;
    int r0 = blockIdx.x * 32;
    if (tid < 32 * IN_F) {
        int r = tid / IN_F, f = tid - r * IN_F;
        int row = r0 + r;
        xs[r][f] = (row < NN) ? xin12[(size_t)row * IN_F + f] : 0.f;
    }
    __syncthreads();
    // phase A (VALU): l1[r][j] = BN(relu(xs[r]·W1[j] + b1[j]))
    {
        int j = tid & 127, rb = tid >> 7;
        float sc = gg[j] * rsqrtf(rv[j] + BN_EPS);
        float sh = be[j] - rm[j] * sc;
        float bj = b1[j];
        float wreg[IN_F];
#pragma unroll
        for (int k = 0; k < IN_F; ++k) wreg[k] = W1[j * IN_F + k];
#pragma unroll
        for (int q = 0; q < 8; ++q) {
            int r = rb + q * 4;
            float s = bj;
#pragma unroll
            for (int k = 0; k < IN_F; ++k) s += xs[r][k] * wreg[k];
            s = fmaxf(s, 0.f);
            l1[r][j] = f2b(s * sc + sh);
        }
    }
    __syncthreads();
    // phase B (MFMA): l2 = relu(l1 @ w2b^T + b2)
    {
        int j0 = wave * 16;
        const ushort_t* pw = w2b + (size_t)(j0 + li) * HID + ks * 8;
        f32x4 acc0 = {0,0,0,0}, acc1 = {0,0,0,0};
#pragma unroll
        for (int k0 = 0; k0 < HID; k0 += 32) {
            bf16x8 w = *(const bf16x8*)(pw + k0);
            bf16x8 a0 = *(const bf16x8*)&l1[li][ks * 8 + k0];
            bf16x8 a1 = *(const bf16x8*)&l1[li + 16][ks * 8 + k0];
            acc0 = MFMA(a0, w, acc0);
            acc1 = MFMA(a1, w, acc1);
        }
        float bj = b2[j0 + li];
#pragma unroll
        for (int q = 0; q < 4; ++q) {
            l2[ks * 4 + q][j0 + li] = f2b(fmaxf(acc0[q] + bj, 0.f));
            l2[16 + ks * 4 + q][j0 + li] = f2b(fmaxf(acc1[q] + bj, 0.f));
        }
    }
    __syncthreads();
    gru_phase(l2, h, wih, whh, bih, bhh, r0, li, ks, wave);
}

// ---------------- mega2: c2-layer1 MFMA(BN) -> LDS -> c2-layer2 MFMA -> LDS -> GRU2 ----------------
__global__ __launch_bounds__(512) void mega2_kernel(const ushort_t* __restrict__ xin2,
                                                    ushort_t* __restrict__ h,
                                                    const ushort_t* __restrict__ w1b, const float* __restrict__ b1,
                                                    const float* __restrict__ gg, const float* __restrict__ be,
                                                    const float* __restrict__ rm, const float* __restrict__ rv,
                                                    const ushort_t* __restrict__ w2b, const float* __restrict__ b2,
                                                    const ushort_t* __restrict__ wih, const ushort_t* __restrict__ whh,
                                                    const float* __restrict__ bih, const float* __restrict__ bhh) {
    __shared__ ushort_t l1[32][LPAD];
    __shared__ ushort_t l2[32][LPAD];
    int tid = threadIdx.x;
    int wave = tid >> 6, lane = tid & 63;
    int li = lane & 15, ks = lane >> 4;
    int r0 = blockIdx.x * 32;
    // phase A (MFMA from global): l1 = BN(relu(xin2 @ w1b^T + b1))
    {
        int j0 = wave * 16;
        int ra0 = min(r0 + li, NN - 1);
        int ra1 = min(r0 + 16 + li, NN - 1);
        const ushort_t* pa0 = xin2 + (size_t)ra0 * HID + ks * 8;
        const ushort_t* pa1 = xin2 + (size_t)ra1 * HID + ks * 8;
        const ushort_t* pw = w1b + (size_t)(j0 + li) * HID + ks * 8;
        f32x4 acc0 = {0,0,0,0}, acc1 = {0,0,0,0};
#pragma unroll
        for (int k0 = 0; k0 < HID; k0 += 32) {
            bf16x8 w = *(const bf16x8*)(pw + k0);
            bf16x8 a0 = *(const bf16x8*)(pa0 + k0);
            bf16x8 a1 = *(const bf16x8*)(pa1 + k0);
            acc0 = MFMA(a0, w, acc0);
            acc1 = MFMA(a1, w, acc1);
        }
        int jc = j0 + li;
        float sc = gg[jc] * rsqrtf(rv[jc] + BN_EPS);
        float sh = be[jc] - rm[jc] * sc;
        float bj = b1[jc];
#pragma unroll
        for (int q = 0; q < 4; ++q) {
            l1[ks * 4 + q][jc] = f2b(fmaxf(acc0[q] + bj, 0.f) * sc + sh);
            l1[16 + ks * 4 + q][jc] = f2b(fmaxf(acc1[q] + bj, 0.f) * sc + sh);
        }
    }
    __syncthreads();
    // phase B: l2 = relu(l1 @ w2b^T + b2)
    {
        int j0 = wave * 16;
        const ushort_t* pw = w2b + (size_t)(j0 + li) * HID + ks * 8;
        f32x4 acc0 = {0,0,0,0}, acc1 = {0,0,0,0};
#pragma unroll
        for (int k0 = 0; k0 < HID; k0 += 32) {
            bf16x8 w = *(const bf16x8*)(pw + k0);
            bf16x8 a0 = *(const bf16x8*)&l1[li][ks * 8 + k0];
            bf16x8 a1 = *(const bf16x8*)&l1[li + 16][ks * 8 + k0];
            acc0 = MFMA(a0, w, acc0);
            acc1 = MFMA(a1, w, acc1);
        }
        float bj = b2[j0 + li];
#pragma unroll
        for (int q = 0; q < 4; ++q) {
            l2[ks * 4 + q][j0 + li] = f2b(fmaxf(acc0[q] + bj, 0.f));
            l2[16 + ks * 4 + q][j0 + li] = f2b(fmaxf(acc1[q] + bj, 0.f));
        }
    }
    __syncthreads();
    gru_phase(l2, h, wih, whh, bih, bhh, r0, li, ks, wave);
}

// ---------------- conv2 aggregation (128 bf16 features), one wave per node, 4-edge ILP ----------------
__global__ __launch_bounds__(256) void agg128b_kernel(const ushort_t* __restrict__ x,
                                                      const int* __restrict__ rp,
                                                      const int* __restrict__ col,
                                                      ushort_t* __restrict__ out, int E) {
    int node = (blockIdx.x * 256 + threadIdx.x) >> 6;
    int lane = threadIdx.x & 63;
    if (node >= NN) return;
    unsigned v = *(const unsigned*)(x + (size_t)node * HID + lane * 2);
    float s0 = b2f((ushort_t)(v & 0xffff));
    float s1 = b2f((ushort_t)(v >> 16));
    int e0 = rp[node], e1 = rp[node + 1];
    if (e1 > E) e1 = E;
    int e = e0;
    for (; e + 3 < e1; e += 4) {
        unsigned c0 = (unsigned)col[e], c1 = (unsigned)col[e + 1];
        unsigned c2 = (unsigned)col[e + 2], c3 = (unsigned)col[e + 3];
        c0 = (c0 < NN) ? c0 : 0; c1 = (c1 < NN) ? c1 : 0;
        c2 = (c2 < NN) ? c2 : 0; c3 = (c3 < NN) ? c3 : 0;
        unsigned u0 = *(const unsigned*)(x + (size_t)c0 * HID + lane * 2);
        unsigned u1 = *(const unsigned*)(x + (size_t)c1 * HID + lane * 2);
        unsigned u2 = *(const unsigned*)(x + (size_t)c2 * HID + lane * 2);
        unsigned u3 = *(const unsigned*)(x + (size_t)c3 * HID + lane * 2);
        s0 += b2f((ushort_t)(u0 & 0xffff)) + b2f((ushort_t)(u1 & 0xffff))
            + b2f((ushort_t)(u2 & 0xffff)) + b2f((ushort_t)(u3 & 0xffff));
        s1 += b2f((ushort_t)(u0 >> 16)) + b2f((ushort_t)(u1 >> 16))
            + b2f((ushort_t)(u2 >> 16)) + b2f((ushort_t)(u3 >> 16));
    }
    for (; e < e1; ++e) {
        unsigned c = (unsigned)col[e];
        if (c < NN) {
            unsigned u = *(const unsigned*)(x + (size_t)c * HID + lane * 2);
            s0 += b2f((ushort_t)(u & 0xffff));
            s1 += b2f((ushort_t)(u >> 16));
        }
    }
    unsigned o = (unsigned)f2b(s0) | ((unsigned)f2b(s1) << 16);
    *(unsigned*)(out + (size_t)node * HID + lane * 2) = o;
}

// ---------------- head ----------------
__global__ __launch_bounds__(64) void head_kernel(const ushort_t* __restrict__ h2, const int* __restrict__ tidx,
                                                  const float* __restrict__ apart,
                                                  const float* __restrict__ w1, const float* __restrict__ b1,
                                                  const float* __restrict__ w2, const float* __restrict__ b2,
                                                  const float* __restrict__ w3, const float* __restrict__ b3,
                                                  float* __restrict__ out) {
    __shared__ float feat[HID + AF_];
    __shared__ float o1[64];
    __shared__ float o2[32];
    int b = blockIdx.x;
    int t = threadIdx.x;
    unsigned node = (unsigned)tidx[b];
    if (node >= NN) node = 0;
    for (int k = t; k < HID; k += 64) feat[k] = b2f(h2[(size_t)node * HID + k]);
    if (t < AF_) feat[HID + t] = apart[(size_t)b * AF_ + t];
    __syncthreads();
    {
        float s = b1[t];
        for (int k = 0; k < HID + AF_; ++k) s += feat[k] * w1[t * (HID + AF_) + k];
        o1[t] = (s > 0.f) ? s : 0.1f * s;
    }
    __syncthreads();
    if (t < 32) {
        float s = b2[t];
        for (int k = 0; k < 64; ++k) s += o1[k] * w2[t * 64 + k];
        o2[t] = (s > 0.f) ? s : 0.05f * s;
    }
    __syncthreads();
    if (t == 0) {
        float s = b3[0];
        for (int k = 0; k < 32; ++k) s += o2[k] * w3[k];
        out[b] = s;
    }
}

extern "C" void kernel_launch(void* const* d_in, const int* in_sizes, int n_in,
                              void* d_out, int out_size, void* d_ws, size_t ws_size,
                              hipStream_t stream) {
    // ---- strict input-mapping validation ----
    int ie_src = -1, ie_dst = -1, ie_tidx = -1, iw0 = -1;
    bool ok = false;
    if (n_in >= 31 && in_sizes[0] == T_STEPS * NN * IN_F && in_sizes[1] == BB * AF_) {
        if (in_sizes[2] > 100000 && in_sizes[3] == in_sizes[2] && in_sizes[4] == BB &&
            in_sizes[5] == HID * IN_F && in_sizes[11] == HID * HID &&
            in_sizes[21] == G3 * HID && in_sizes[22] == G3 * HID &&
            in_sizes[25] == 64 * (HID + AF_)) {
            ie_src = 2; ie_dst = 3; ie_tidx = 4; iw0 = 5; ok = true;
        } else if (in_sizes[2] == HID * IN_F && in_sizes[8] == HID * HID &&
                   in_sizes[18] == G3 * HID && in_sizes[19] == G3 * HID &&
                   in_sizes[22] == 64 * (HID + AF_) &&
                   in_sizes[28] > 100000 && in_sizes[29] == in_sizes[28] && in_sizes[30] == BB) {
            iw0 = 2; ie_src = 28; ie_dst = 29; ie_tidx = 30; ok = true;
        }
    }
    if (!ok) {
        zero_out_kernel<<<(out_size + 255) / 256, 256, 0, stream>>>((float*)d_out, out_size);
        return;
    }

    const float* x_seq  = (const float*)d_in[0];
    const float* apart  = (const float*)d_in[1];
    const int*   e_src  = (const int*)d_in[ie_src];
    const int*   e_dst  = (const int*)d_in[ie_dst];
    const int*   t_idx  = (const int*)d_in[ie_tidx];
    const float* c1_w1 = (const float*)d_in[iw0 + 0];
    const float* c1_b1 = (const float*)d_in[iw0 + 1];
    const float* c1_g  = (const float*)d_in[iw0 + 2];
    const float* c1_be = (const float*)d_in[iw0 + 3];
    const float* c1_rm = (const float*)d_in[iw0 + 4];
    const float* c1_rv = (const float*)d_in[iw0 + 5];
    const float* c1_w2 = (const float*)d_in[iw0 + 6];
    const float* c1_b2 = (const float*)d_in[iw0 + 7];
    const float* c2_w1 = (const float*)d_in[iw0 + 8];
    const float* c2_b1 = (const float*)d_in[iw0 + 9];
    const float* c2_g  = (const float*)d_in[iw0 + 10];
    const float* c2_be = (const float*)d_in[iw0 + 11];
    const float* c2_rm = (const float*)d_in[iw0 + 12];
    const float* c2_rv = (const float*)d_in[iw0 + 13];
    const float* c2_w2 = (const float*)d_in[iw0 + 14];
    const float* c2_b2 = (const float*)d_in[iw0 + 15];
    const float* g_wih = (const float*)d_in[iw0 + 16];
    const float* g_whh = (const float*)d_in[iw0 + 17];
    const float* g_bih = (const float*)d_in[iw0 + 18];
    const float* g_bhh = (const float*)d_in[iw0 + 19];
    const float* f1_w  = (const float*)d_in[iw0 + 20];
    const float* f1_b  = (const float*)d_in[iw0 + 21];
    const float* f2_w  = (const float*)d_in[iw0 + 22];
    const float* f2_b  = (const float*)d_in[iw0 + 23];
    const float* f3_w  = (const float*)d_in[iw0 + 24];
    const float* f3_b  = (const float*)d_in[iw0 + 25];

    int E = in_sizes[ie_src];
    if (E > EE) E = EE;

    // ---- scratch ----
    char* base;
    if (ws_size >= WS_NEED) {
        base = (char*)d_ws;
    } else {
        void* sp = nullptr;
        hipGetSymbolAddress(&sp, HIP_SYMBOL(g_static_pool));
        if (sp == nullptr) {
            zero_out_kernel<<<(out_size + 255) / 256, 256, 0, stream>>>((float*)d_out, out_size);
            return;
        }
        base = (char*)sp;
    }
    size_t off = 0;
    auto nxt = [&](size_t bytes) { char* p = base + off; off += bytes; return p; };
    int*      deg     = (int*)nxt(SZ_DEG);
    int*      row_ptr = (int*)nxt(SZ_RP);
    int*      cursor  = (int*)nxt(SZ_CUR);
    int*      col     = (int*)nxt(SZ_COL);
    float*    xin12   = (float*)nxt(SZ_XIN12);
    ushort_t* xin2    = (ushort_t*)nxt(SZ_NHB);
    ushort_t* h1      = (ushort_t*)nxt(SZ_NHB);
    ushort_t* h2      = (ushort_t*)nxt(SZ_NHB);
    ushort_t* wb_c1w2 = (ushort_t*)nxt(SZ_W128);
    ushort_t* wb_c2w1 = (ushort_t*)nxt(SZ_W128);
    ushort_t* wb_c2w2 = (ushort_t*)nxt(SZ_W128);
    ushort_t* wb_wih  = (ushort_t*)nxt(SZ_WGRU);
    ushort_t* wb_whh  = (ushort_t*)nxt(SZ_WGRU);

    const int NW = 3 * HID * HID + 2 * G3 * HID;
    cvt5_kernel<<<(NW + 255) / 256, 256, 0, stream>>>(c1_w2, wb_c1w2, HID * HID,
                                                      c2_w1, wb_c2w1, HID * HID,
                                                      c2_w2, wb_c2w2, HID * HID,
                                                      g_wih, wb_wih, G3 * HID,
                                                      g_whh, wb_whh, G3 * HID);

    init_kernel<<<(NN * HID + 255) / 256, 256, 0, stream>>>(deg, h1, h2);

    hist_kernel<<<(E + 255) / 256, 256, 0, stream>>>(e_dst, deg, E);
    scan_kernel<<<1, 1024, 0, stream>>>(deg, row_ptr, cursor, NN);
    scatter_kernel<<<(E + 255) / 256, 256, 0, stream>>>(e_src, e_dst, cursor, col, E);

    const int mgrid = (NN + 31) / 32;  // 32 rows/block

    for (int t = 0; t < T_STEPS; ++t) {
        const float* xt = x_seq + (size_t)t * NN * IN_F;
        agg12_kernel<<<(NN * IN_F + 255) / 256, 256, 0, stream>>>(xt, row_ptr, col, xin12, E);
        mega1_kernel<<<mgrid, 512, 0, stream>>>(xin12, h1,
                                                c1_w1, c1_b1, c1_g, c1_be, c1_rm, c1_rv,
                                                wb_c1w2, c1_b2,
                                                wb_wih, wb_whh, g_bih, g_bhh);
        agg128b_kernel<<<(NN * 64 + 255) / 256, 256, 0, stream>>>(h1, row_ptr, col, xin2, E);
        mega2_kernel<<<mgrid, 512, 0, stream>>>(xin2, h2,
                                                wb_c2w1, c2_b1, c2_g, c2_be, c2_rm, c2_rv,
                                                wb_c2w2, c2_b2,
                                                wb_wih, wb_whh, g_bih, g_bhh);
    }

    head_kernel<<<BB, 64, 0, stream>>>(h2, t_idx, apart, f1_w, f1_b, f2_w, f2_b, f3_w, f3_b, (float*)d_out);
}